// Round 12
// baseline (341.548 us; speedup 1.0000x reference)
//
#include <hip/hip_runtime.h>

// ---------------------------------------------------------------------------
// SelfAttention (GQA + nonstandard RoPE), S=2048, HIDDEN=2048, 32 q-heads,
// 8 kv-heads, D=64.  Inputs/outputs FLOAT32; internal bf16 MFMA, fp32 accum.
// R12: GEMM B-operand bypasses LDS: global->VGPR b128 loads, register
// double-buffered across iterations (loads stay in flight across the
// barrier — reg loads aren't drained by __syncthreads).  LDS holds only A
// (16 KB dbuf).  LDS traffic/iter drops ~3x.  Flash/prep/combine = R11.
// ---------------------------------------------------------------------------

typedef __bf16 bf16_t;
typedef __bf16 bf16x4 __attribute__((ext_vector_type(4)));
typedef __bf16 bf16x8 __attribute__((ext_vector_type(8)));
typedef float  f32x4  __attribute__((ext_vector_type(4)));
typedef short  s16x4  __attribute__((ext_vector_type(4)));

#define S_LEN   2048
#define HID     2048
#define NKV     8
#define NH      32
#define DHEAD   64
#define KVW     (NKV * DHEAD)   // 512

// ---- module-global scratch (rewritten fully each call) ---------------------
__device__ __align__(16) bf16_t g_xb [S_LEN * HID];     // x in bf16
__device__ __align__(16) bf16_t g_wTq[HID * HID];       // q_proj^T  [N][K]
__device__ __align__(16) bf16_t g_wTk[KVW * HID];       // k_proj^T
__device__ __align__(16) bf16_t g_wTv[KVW * HID];       // v_proj^T
__device__ __align__(16) bf16_t g_wTo[HID * HID];       // o_proj^T
__device__ __align__(16) bf16_t g_q [S_LEN * HID];      // roped Q
__device__ __align__(16) bf16_t g_k [S_LEN * KVW];      // roped K
__device__ __align__(16) bf16_t g_vT[KVW * S_LEN];      // V^T [d_total][S]
__device__ __align__(16) bf16_t g_om[S_LEN * HID];      // attn out (pre o_proj)
__device__ float g_ropeC[S_LEN * 32];
__device__ float g_ropeS[S_LEN * 32];
__device__ __align__(16) float g_po[4u * S_LEN * HID];  // partial O, per key-chunk
__device__ float g_pl[4u * S_LEN * NH];                 // partial l

static __device__ inline s16x4 bc4(bf16x4 v) { s16x4 r; __builtin_memcpy(&r, &v, 8); return r; }

// async 16B global -> LDS.  lds base wave-uniform; data lands at base+lane*16.
__device__ __forceinline__ void gll16(void* lds, const void* g) {
    __builtin_amdgcn_global_load_lds(
        (const __attribute__((address_space(1))) void*)g,
        (__attribute__((address_space(3))) void*)lds,
        16, 0, 0);
}

// ---------------------------------------------------------------------------
// prep: (a) RoPE table (f64-exact; inv_freq dtype sniff), (b) x f32->bf16,
// (c) four weight transposes f32 [R][C] -> bf16 [C][R].
// ---------------------------------------------------------------------------
__global__ __launch_bounds__(256)
void prep_kernel(const float* __restrict__ x,
                 const float* __restrict__ qw, const float* __restrict__ kw,
                 const float* __restrict__ vw, const float* __restrict__ ow,
                 const void* __restrict__ invf_raw) {
    __shared__ bf16_t tile[64][65];
    int b = blockIdx.x, t = threadIdx.x;

    if (b < 256) {                               // RoPE table: 65536 entries
        int idx = b * 256 + t;
        int s = idx >> 5, j = idx & 31;
        float f;
        if (*(const unsigned*)invf_raw == 0x3F800000u) {
            f = ((const float*)invf_raw)[j];
        } else {
            unsigned u = ((unsigned)((const unsigned short*)invf_raw)[j]) << 16;
            __builtin_memcpy(&f, &u, 4);
        }
        double a = (double)s * (double)f;
        g_ropeC[idx] = (float)cos(a);
        g_ropeS[idx] = (float)sin(a);
        return;
    }
    if (b < 4352) {                              // x convert: 1M float4
        int idx = (b - 256) * 256 + t;
        float4 v = reinterpret_cast<const float4*>(x)[idx];
        bf16x4 o;
        o[0] = (bf16_t)v.x; o[1] = (bf16_t)v.y; o[2] = (bf16_t)v.z; o[3] = (bf16_t)v.w;
        *reinterpret_cast<bf16x4*>(&g_xb[(size_t)idx * 4]) = o;
        return;
    }
    const float* in; bf16_t* outp; int R, C, tb;
    if (b < 5376)      { in = qw; outp = g_wTq; R = HID; C = HID; tb = b - 4352; }
    else if (b < 5632) { in = kw; outp = g_wTk; R = HID; C = KVW; tb = b - 5376; }
    else if (b < 5888) { in = vw; outp = g_wTv; R = HID; C = KVW; tb = b - 5632; }
    else               { in = ow; outp = g_wTo; R = HID; C = HID; tb = b - 5888; }
    int xt = C >> 6;
    int c0 = (tb % xt) * 64, r0 = (tb / xt) * 64;
    int tx = t & 63, ty = t >> 6;
    #pragma unroll
    for (int r = ty; r < 64; r += 4)
        tile[r][tx] = (bf16_t)in[(size_t)(r0 + r) * C + c0 + tx];
    __syncthreads();
    #pragma unroll
    for (int r = ty; r < 64; r += 4)
        outp[(size_t)(c0 + r) * R + r0 + tx] = tile[tx][r];
}

// ---------------------------------------------------------------------------
// Fused MFMA GEMM, 64x128 block tile, BK=64.  A: LDS dbuf via gll16 (XOR
// octet swizzle).  B: global->VGPR b128, register double-buffered (issued
// one iteration ahead; not drained by barriers).
// which=0: QKV fused over bx (0-15 Q+RoPE, 16-19 K+RoPE, 20-23 V transp).
// which=1: O, f32 out.
// ---------------------------------------------------------------------------
__global__ __launch_bounds__(256)
void gemm_fused_kernel(float* __restrict__ Cf, int which) {
    __shared__ __align__(16) bf16_t As[2][64 * 64];     // 8 KB per buf

    int t    = threadIdx.x;
    int lane = t & 63, wid = t >> 6;
    int quad = lane >> 4, l15 = lane & 15;
    int bx = blockIdx.x, m0 = blockIdx.y * 64;
    int wm = (wid >> 1) * 32, wn = (wid & 1) * 64;

    const bf16_t* A; const bf16_t* Bt; int n0;
    if (which == 1)      { A = g_om; Bt = g_wTo; n0 = bx * 128; }
    else {
        A = g_xb;
        if (bx < 16)      { Bt = g_wTq; n0 = bx * 128; }
        else if (bx < 20) { Bt = g_wTk; n0 = (bx - 16) * 128; }
        else              { Bt = g_wTv; n0 = (bx - 20) * 128; }
    }

    int crow = lane >> 3;                        // row within 8-row chunk
    int gseg = (lane & 7) ^ crow;                // swizzled 16B source octet
    int so   = l15 & 7;                          // read-side row swizzle key
    const bf16_t* brow = Bt + (size_t)(n0 + wn + l15) * HID + quad * 8;

    f32x4 acc[2][4];
    #pragma unroll
    for (int im = 0; im < 2; ++im)
        #pragma unroll
        for (int in = 0; in < 4; ++in)
            #pragma unroll
            for (int r = 0; r < 4; ++r) acc[im][in][r] = 0.f;

    auto stageA = [&](int buf, int kt) {
        gll16(&As[buf][(wid * 2 + 0) * 512], A + (size_t)(m0 + (wid * 2 + 0) * 8 + crow) * HID + kt + gseg * 8);
        gll16(&As[buf][(wid * 2 + 1) * 512], A + (size_t)(m0 + (wid * 2 + 1) * 8 + crow) * HID + kt + gseg * 8);
    };
    auto loadB = [&](bf16x8 (&br)[4][2], int kt) {
        #pragma unroll
        for (int in = 0; in < 4; ++in)
            #pragma unroll
            for (int kh = 0; kh < 2; ++kh)
                br[in][kh] = *reinterpret_cast<const bf16x8*>(brow + (size_t)in * 16 * HID + kt + kh * 32);
    };
    auto compute = [&](const bf16_t* Abuf, bf16x8 (&br)[4][2]) {
        bf16x8 af[2][2];
        #pragma unroll
        for (int im = 0; im < 2; ++im)
            #pragma unroll
            for (int kh = 0; kh < 2; ++kh)
                af[im][kh] = *reinterpret_cast<const bf16x8*>(
                    &Abuf[(wm + im * 16 + l15) * 64 + (((kh * 4 + quad) ^ so) * 8)]);
        #pragma unroll
        for (int im = 0; im < 2; ++im)
            #pragma unroll
            for (int in = 0; in < 4; ++in)
                #pragma unroll
                for (int kh = 0; kh < 2; ++kh)
                    acc[im][in] = __builtin_amdgcn_mfma_f32_16x16x32_bf16(
                        af[im][kh], br[in][kh], acc[im][in], 0, 0, 0);
    };

    bf16x8 b0[4][2], b1[4][2];
    stageA(0, 0);
    loadB(b0, 0);

    for (int it = 0; it < 32; it += 2) {
        __syncthreads();                          // As[0] ready
        if (it + 1 < 32) { stageA(1, (it + 1) * 64); loadB(b1, (it + 1) * 64); }
        compute(&As[0][0], b0);
        __syncthreads();                          // As[1] ready; As[0] free
        if (it + 2 < 32) { stageA(0, (it + 2) * 64); loadB(b0, (it + 2) * 64); }
        compute(&As[1][0], b1);
    }

    if (which == 1) {                            // O: f32 row-major
        #pragma unroll
        for (int im = 0; im < 2; ++im) {
            int rowb = m0 + wm + im * 16 + quad * 4;
            #pragma unroll
            for (int in = 0; in < 4; ++in) {
                int col = bx * 128 + wn + in * 16 + l15;
                #pragma unroll
                for (int r = 0; r < 4; ++r)
                    Cf[(size_t)(rowb + r) * HID + col] = acc[im][in][r];
            }
        }
    } else if (bx < 20) {                        // Q/K: RoPE epilogue -> bf16
        bf16_t* Cb; int N, colbase;
        if (bx < 16) { Cb = g_q; N = HID; colbase = bx * 128 + wn; }
        else         { Cb = g_k; N = KVW; colbase = (bx - 16) * 128 + wn; }
        // out[d] = x[d]*cos + x[d+32]*sin ; out[d+32] = x[d]*sin - x[d+32]*cos
        #pragma unroll
        for (int im = 0; im < 2; ++im) {
            #pragma unroll
            for (int r = 0; r < 4; ++r) {
                int row = m0 + wm + im * 16 + quad * 4 + r;
                #pragma unroll
                for (int in = 0; in < 2; ++in) {
                    int d = in * 16 + l15;                 // 0..31
                    float a  = acc[im][in][r];
                    float bb = acc[im][in + 2][r];
                    float cc = g_ropeC[row * 32 + d];
                    float ss = g_ropeS[row * 32 + d];
                    Cb[(size_t)row * N + colbase + d]      = (bf16_t)(a * cc + bb * ss);
                    Cb[(size_t)row * N + colbase + 32 + d] = (bf16_t)(a * ss - bb * cc);
                }
            }
        }
    } else {                                     // V: transposed store -> g_vT
        #pragma unroll
        for (int im = 0; im < 2; ++im) {
            int rowb = m0 + wm + im * 16 + quad * 4;
            #pragma unroll
            for (int in = 0; in < 4; ++in) {
                int col = (bx - 20) * 128 + wn + in * 16 + l15;
                #pragma unroll
                for (int r = 0; r < 4; ++r)
                    g_vT[(size_t)col * S_LEN + (rowb + r)] = (bf16_t)acc[im][in][r];
            }
        }
    }
}

// ---------------------------------------------------------------------------
// Flash attention, key-chunked partials (causal, GQA, register-only P).
// Block (hk, qb32, chunk) processes key tiles [8*chunk, min(8*chunk+8, nkt)).
// Fixed-shift softmax p=exp(s-16) is linear over key chunks -> raw f32
// (O, l) partials add in the combine.
// ---------------------------------------------------------------------------
__global__ __launch_bounds__(256)
void flash_part_kernel() {
    __shared__ __align__(16) bf16_t Ks[64][72];   // [key][d]
    __shared__ __align__(16) bf16_t Vs[64][72];   // [d][key]

    int t    = threadIdx.x;
    int lane = t & 63, wid = t >> 6;
    int quad = lane >> 4, l15 = lane & 15;
    int bx   = blockIdx.x;
    int hk   = bx & 7;
    int qb32 = (bx >> 3) & 63;
    int chunk = bx >> 9;                  // 0..3
    int nkt  = (qb32 >> 1) + 1;           // 64-key tiles covering k <= q0+31
    int kt0  = chunk * 8;
    if (kt0 >= nkt) return;               // empty chunk (before any barrier)
    int kt1  = min(kt0 + 8, nkt);

    int head = hk * 4 + wid;
    int q0   = qb32 * 32;

    bf16x8 aq[2][2];
    #pragma unroll
    for (int mq = 0; mq < 2; ++mq) {
        const bf16_t* qp = g_q + (size_t)(q0 + mq * 16 + l15) * HID + head * 64 + quad * 8;
        aq[mq][0] = *reinterpret_cast<const bf16x8*>(qp);
        aq[mq][1] = *reinterpret_cast<const bf16x8*>(qp + 32);
        #pragma unroll
        for (int j = 0; j < 8; ++j) {
            aq[mq][0][j] = (bf16_t)((float)aq[mq][0][j] * 0.125f);  // exact
            aq[mq][1][j] = (bf16_t)((float)aq[mq][1][j] * 0.125f);
        }
    }

    bf16x4 ones4;
    #pragma unroll
    for (int j = 0; j < 4; ++j) ones4[j] = (bf16_t)1.0f;
    s16x4 ones_s = bc4(ones4);

    f32x4 oacc[2][4], liacc[2];
    #pragma unroll
    for (int mq = 0; mq < 2; ++mq) {
        #pragma unroll
        for (int r = 0; r < 4; ++r) liacc[mq][r] = 0.f;
        #pragma unroll
        for (int dt = 0; dt < 4; ++dt)
            #pragma unroll
            for (int r = 0; r < 4; ++r) oacc[mq][dt][r] = 0.f;
    }

    int qcol[2] = { q0 + l15, q0 + 16 + l15 };

    for (int kt = kt0; kt < kt1; ++kt) {
        int k0 = kt * 64;
        __syncthreads();
        #pragma unroll
        for (int i = t; i < 512; i += 256) {
            int row = i >> 3, seg = i & 7;
            *reinterpret_cast<int4*>(&Ks[row][seg * 8]) =
                *reinterpret_cast<const int4*>(g_k + (size_t)(k0 + row) * KVW + hk * 64 + seg * 8);
            *reinterpret_cast<int4*>(&Vs[row][seg * 8]) =
                *reinterpret_cast<const int4*>(g_vT + (size_t)(hk * 64 + row) * S_LEN + k0 + seg * 8);
        }
        __syncthreads();

        bf16x8 ak[4][2];
        #pragma unroll
        for (int mk = 0; mk < 4; ++mk) {
            ak[mk][0] = *reinterpret_cast<const bf16x8*>(&Ks[mk * 16 + l15][quad * 8]);
            ak[mk][1] = *reinterpret_cast<const bf16x8*>(&Ks[mk * 16 + l15][32 + quad * 8]);
        }

        f32x4 sacc[4][2];
        #pragma unroll
        for (int mk = 0; mk < 4; ++mk)
            #pragma unroll
            for (int mq = 0; mq < 2; ++mq) {
                f32x4 s;
                #pragma unroll
                for (int r = 0; r < 4; ++r) s[r] = 0.f;
                s = __builtin_amdgcn_mfma_f32_16x16x32_bf16(ak[mk][0], aq[mq][0], s, 0, 0, 0);
                s = __builtin_amdgcn_mfma_f32_16x16x32_bf16(ak[mk][1], aq[mq][1], s, 0, 0, 0);
                sacc[mk][mq] = s;
            }

        s16x4 pas[4][2];
        #pragma unroll
        for (int mk = 0; mk < 4; ++mk)
            #pragma unroll
            for (int mq = 0; mq < 2; ++mq) {
                bf16x4 pa;
                #pragma unroll
                for (int r = 0; r < 4; ++r) {
                    int kk = k0 + mk * 16 + quad * 4 + r;
                    pa[r] = (bf16_t)((kk <= qcol[mq]) ? __expf(sacc[mk][mq][r] - 16.0f) : 0.0f);
                }
                pas[mk][mq] = bc4(pa);
            }

        #pragma unroll
        for (int mk = 0; mk < 4; ++mk) {
            #pragma unroll
            for (int dt = 0; dt < 4; ++dt) {
                bf16x4 bv = *reinterpret_cast<const bf16x4*>(&Vs[dt * 16 + l15][mk * 16 + quad * 4]);
                s16x4 bvs = bc4(bv);
                #pragma unroll
                for (int mq = 0; mq < 2; ++mq)
                    oacc[mq][dt] = __builtin_amdgcn_mfma_f32_16x16x16bf16_1k(pas[mk][mq], bvs, oacc[mq][dt], 0, 0, 0);
            }
            #pragma unroll
            for (int mq = 0; mq < 2; ++mq)
                liacc[mq] = __builtin_amdgcn_mfma_f32_16x16x16bf16_1k(pas[mk][mq], ones_s, liacc[mq], 0, 0, 0);
        }
    }

    // store raw partials (f32): O row(q)=q0+mq*16+quad*4+r, col(d)=dt*16+l15.
    float* po = g_po + (size_t)chunk * S_LEN * HID;
    #pragma unroll
    for (int mq = 0; mq < 2; ++mq)
        #pragma unroll
        for (int r = 0; r < 4; ++r) {
            int row = q0 + mq * 16 + quad * 4 + r;
            #pragma unroll
            for (int dt = 0; dt < 4; ++dt)
                po[(size_t)row * HID + head * 64 + dt * 16 + l15] = oacc[mq][dt][r];
            if (l15 == 0)
                g_pl[((size_t)chunk * S_LEN + row) * NH + head] = liacc[mq][r];
        }
}

// ---------------------------------------------------------------------------
// Combine partials: g_om[q][hd] = (sum_c O_c) / (sum_c l_c), cast bf16.
// ---------------------------------------------------------------------------
__global__ __launch_bounds__(256)
void flash_combine_kernel() {
    int t = blockIdx.x * 256 + threadIdx.x;      // 0 .. 1M-1
    int row  = t >> 9;                           // q
    int col4 = (t & 511) * 4;                    // d-group
    int head = col4 >> 6;
    int nkt  = ((row >> 5) >> 1) + 1;
    int nc   = (nkt + 7) >> 3;                   // 1..4 chunks

    float4 s = make_float4(0.f, 0.f, 0.f, 0.f);
    float l = 0.f;
    for (int c = 0; c < nc; ++c) {
        const float4 v = *reinterpret_cast<const float4*>(
            g_po + ((size_t)c * S_LEN + row) * HID + col4);
        s.x += v.x; s.y += v.y; s.z += v.z; s.w += v.w;
        l += g_pl[((size_t)c * S_LEN + row) * NH + head];
    }
    float inv = 1.0f / l;
    bf16x4 o;
    o[0] = (bf16_t)(s.x * inv); o[1] = (bf16_t)(s.y * inv);
    o[2] = (bf16_t)(s.z * inv); o[3] = (bf16_t)(s.w * inv);
    *reinterpret_cast<bf16x4*>(&g_om[(size_t)row * HID + col4]) = o;
}

// ---------------------------------------------------------------------------
// Launch: 5 dispatches.
// ---------------------------------------------------------------------------
extern "C" void kernel_launch(void* const* d_in, const int* in_sizes, int n_in,
                              void* d_out, int out_size, void* d_ws, size_t ws_size,
                              hipStream_t stream) {
    const float* x    = (const float*)d_in[0];
    const float* qpW  = (const float*)d_in[1];
    const float* kpW  = (const float*)d_in[2];
    const float* vpW  = (const float*)d_in[3];
    const float* opW  = (const float*)d_in[4];
    const void*  invf = d_in[5];
    float* out = (float*)d_out;

    prep_kernel<<<6912, 256, 0, stream>>>(x, qpW, kpW, vpW, opW, invf);
    gemm_fused_kernel<<<dim3(24, 32), 256, 0, stream>>>(nullptr, 0);   // QKV
    flash_part_kernel<<<2048, 256, 0, stream>>>();                     // 8kv x 64qb x 4chunk
    flash_combine_kernel<<<4096, 256, 0, stream>>>();
    gemm_fused_kernel<<<dim3(16, 32), 256, 0, stream>>>(out, 1);       // O
}